// Round 15
// baseline (54.194 us; speedup 1.0000x reference)
//
#include <hip/hip_runtime.h>
#include <hip/hip_bf16.h>

typedef short bf16x8 __attribute__((ext_vector_type(8)));
typedef float f32x4  __attribute__((ext_vector_type(4)));

constexpr int HW = 4096;   // 64*64 pixels
constexpr int CT = 31;     // time channels
constexpr int CP = 128;    // poi channels
constexpr int CO = 64;     // output channels

__device__ __forceinline__ short f2bf(float x) {
    __hip_bfloat16 h = __float2bfloat16(x);
    return *reinterpret_cast<short*>(&h);
}
__device__ __forceinline__ unsigned int f2bfu(float x) {
    __hip_bfloat16 h = __float2bfloat16(x);
    return (unsigned int)*reinterpret_cast<unsigned short*>(&h);
}

// Wave = 32-px strip (2 tiles); block = 4 waves = 128 px; grid = 1024 blocks.
// wc lives as bf16 in LDS (16 KiB, shared by the block) -> frees 64 VGPRs/wave
// so the 40 per-tile global loads can ALL be hoisted (sched_barrier pins them).
// B-fragment = ds_read_b128, bank-conflict-free (same-m broadcast, g-groups
// hit disjoint bank quartets). Stores: contiguous 128 B per o-row, nontemporal.
__global__ __launch_bounds__(256, 4)
void poi_mfma4(const float* __restrict__ poi,
               const float* __restrict__ tin,
               const float* __restrict__ wm,
               const float* __restrict__ bm,
               const float* __restrict__ wf,
               const float* __restrict__ bf,
               const float* __restrict__ wc,
               const float* __restrict__ bc,
               float* __restrict__ out)
{
    __shared__ __align__(16) unsigned short s_wc[CO * CP];   // bf16, 16 KiB

    const int tid  = threadIdx.x;
    const int lane = tid & 63;
    const int m    = lane & 15;       // free index: o (B,D-col) / px (A-row)
    const int g    = lane >> 4;       // 4-lane group: k-subrange / D row-group
    const int wid  = tid >> 6;
    const int b    = blockIdx.x >> 5;                       // 32 blocks per image
    const int px0  = ((blockIdx.x & 31) << 7) + wid * 32;   // wave strip base

    // ---- cooperative wc -> LDS (f32 pairs -> packed bf16), coalesced ----
    {
        unsigned int* d = reinterpret_cast<unsigned int*>(s_wc);
        const float2* s = reinterpret_cast<const float2*>(wc);
        #pragma unroll
        for (int i = 0; i < (CO * CP / 2) / 256; ++i) {     // 16 iters
            const int idx = i * 256 + tid;
            const float2 w2 = s[idx];
            d[idx] = f2bfu(w2.x) | (f2bfu(w2.y) << 16);
        }
    }

    // ---- small per-wave weights (stage 1) ----
    bf16x8 wmf[2];                    // wm: 32x31 padded to 32x32 (A operand)
    #pragma unroll
    for (int t2 = 0; t2 < 2; ++t2)
      #pragma unroll
      for (int j = 0; j < 8; ++j) {
        const int c = g * 8 + j;
        wmf[t2][j] = (c < CT) ? f2bf(wm[(t2 * 16 + m) * CT + c]) : (short)0;
      }
    float wff[8]; f32x4 bmf[2]; float bcf[4];
    #pragma unroll
    for (int t2 = 0; t2 < 2; ++t2)
      #pragma unroll
      for (int r = 0; r < 4; ++r) {
        wff[t2 * 4 + r] = wf[t2 * 16 + g * 4 + r];
        bmf[t2][r]      = bm[t2 * 16 + g * 4 + r];
      }
    #pragma unroll
    for (int s = 0; s < 4; ++s) bcf[s] = bc[s * 16 + m];    // o = s*16 + m
    const float bfv = bf[0];

    __syncthreads();                  // s_wc ready

    const float* tbase = tin + (size_t)b * CT * HW;
    const float* pbase = poi + (size_t)b * CP * HW;
    float*       obase = out + (size_t)b * CO * HW;

    #pragma unroll
    for (int t = 0; t < 2; ++t) {
        const int pxt = px0 + t * 16;
        const float* tb = tbase + pxt + m;
        const float* pb = pbase + pxt + m;

        // ---- issue ALL 40 tile loads up front (tf first: consumed first) ----
        float tfr[8];
        #pragma unroll
        for (int j = 0; j < 8; ++j) {
            const int c = g * 8 + j;
            tfr[j] = (c < CT) ? tb[(size_t)c * HW] : 0.f;
        }
        float pfr[32];
        #pragma unroll
        for (int kf = 0; kf < 4; ++kf)
          #pragma unroll
          for (int j = 0; j < 8; ++j)
            pfr[kf * 8 + j] = pb[(size_t)(kf * 32 + g * 8 + j) * HW];
        __builtin_amdgcn_sched_barrier(0);   // nothing crosses: loads stay hoisted

        // ---- stage 1: tval = relu(wf . relu(wm@time + bm) + bf) ----
        bf16x8 tf;
        #pragma unroll
        for (int j = 0; j < 8; ++j) tf[j] = f2bf(tfr[j]);
        f32x4 z0 = __builtin_amdgcn_mfma_f32_16x16x32_bf16(wmf[0], tf, bmf[0], 0, 0, 0);
        f32x4 z1 = __builtin_amdgcn_mfma_f32_16x16x32_bf16(wmf[1], tf, bmf[1], 0, 0, 0);
        float s1 = 0.f;
        #pragma unroll
        for (int r = 0; r < 4; ++r) {
            s1 = fmaf(fmaxf(z0[r], 0.f), wff[r],     s1);
            s1 = fmaf(fmaxf(z1[r], 0.f), wff[4 + r], s1);
        }
        s1 += __shfl_xor(s1, 16, 64);
        s1 += __shfl_xor(s1, 32, 64);
        const float tval = fmaxf(s1 + bfv, 0.f);      // valid for px = pxt + m
        f32x4 tv;                                     // transpose to D-row layout
        #pragma unroll
        for (int r = 0; r < 4; ++r) tv[r] = __shfl(tval, g * 4 + r, 64);

        // ---- stage 2: A = poi (M=px), B = wc from LDS (N=o), K=128 ----
        bf16x8 pfv[4];
        #pragma unroll
        for (int kf = 0; kf < 4; ++kf)
          #pragma unroll
          for (int j = 0; j < 8; ++j)
            pfv[kf][j] = f2bf(pfr[kf * 8 + j]);

        float* ob = obase + pxt + g * 4;              // lane's 4-px store base
        #pragma unroll
        for (int s = 0; s < 4; ++s) {
            f32x4 a = {0.f, 0.f, 0.f, 0.f};
            #pragma unroll
            for (int kf = 0; kf < 4; ++kf) {
                const bf16x8 wv = *reinterpret_cast<const bf16x8*>(
                    &s_wc[(s * 16 + m) * CP + kf * 32 + g * 8]);   // ds_read_b128
                a = __builtin_amdgcn_mfma_f32_16x16x32_bf16(pfv[kf], wv, a, 0, 0, 0);
            }
            f32x4 v;
            #pragma unroll
            for (int r = 0; r < 4; ++r) v[r] = fmaf(tv[r], a[r], bcf[s]);
            __builtin_nontemporal_store(
                v, reinterpret_cast<f32x4*>(ob + (size_t)(s * 16 + m) * HW));
        }
    }
}

extern "C" void kernel_launch(void* const* d_in, const int* in_sizes, int n_in,
                              void* d_out, int out_size, void* d_ws, size_t ws_size,
                              hipStream_t stream) {
    const float* poi = (const float*)d_in[0];
    const float* tin = (const float*)d_in[1];
    const float* wm  = (const float*)d_in[2];
    const float* bm  = (const float*)d_in[3];
    const float* wf  = (const float*)d_in[4];
    const float* bf  = (const float*)d_in[5];
    const float* wc  = (const float*)d_in[6];
    const float* bc  = (const float*)d_in[7];
    float* out = (float*)d_out;

    // 32 images x 32 strips (128 px each) = 1024 blocks of 256 threads
    hipLaunchKernelGGL(poi_mfma4, dim3(1024), dim3(256), 0, stream,
                       poi, tin, wm, bm, wf, bf, wc, bc, out);
}

// Round 16
// 38.707 us; speedup vs baseline: 1.4001x; 1.4001x over previous
//
#include <hip/hip_runtime.h>
#include <hip/hip_bf16.h>

typedef short bf16x8 __attribute__((ext_vector_type(8)));
typedef float f32x4  __attribute__((ext_vector_type(4)));

constexpr int HW = 4096;   // 64*64 pixels
constexpr int CT = 31;     // time channels
constexpr int CP = 128;    // poi channels
constexpr int CO = 64;     // output channels

__device__ __forceinline__ short f2bf(float x) {
    __hip_bfloat16 h = __float2bfloat16(x);
    return *reinterpret_cast<short*>(&h);
}

// o-split variant of the (verified) mfma3 structure, NO LDS:
// wave owns 32 o's (wcf[2][4] = 32 VGPRs instead of 64) x 32 px (2 tiles).
// Waves (2w, 2w+1) share one 32-px strip and split the o-dim -> the second
// wave's poi reads are L1/L2 hits on the same CU. Freed ~40 VGPRs let the
// compiler hoist all 40 per-tile scalar loads (sched_barrier pins them).
// Stores unchanged from mfma3: contiguous 128 B per o-row per wave, nt.
// grid = 32 images * 64 strips = 2048 blocks of 256 threads.
__global__ __launch_bounds__(256)
void poi_mfma5(const float* __restrict__ poi,
               const float* __restrict__ tin,
               const float* __restrict__ wm,
               const float* __restrict__ bm,
               const float* __restrict__ wf,
               const float* __restrict__ bf,
               const float* __restrict__ wc,
               const float* __restrict__ bc,
               float* __restrict__ out)
{
    const int lane = threadIdx.x & 63;
    const int m    = lane & 15;       // free index: o (B,D-col) / px (A-row)
    const int g    = lane >> 4;       // 4-lane group: k-subrange / D row-group
    const int wid  = threadIdx.x >> 6;
    const int oh   = (wid & 1) * 2;   // this wave's o-subtiles: s in {oh, oh+1}
    const int b    = blockIdx.x >> 6;                        // 64 blocks per image
    const int px0  = ((blockIdx.x & 63) << 6) + (wid >> 1) * 32;  // wave strip

    // ---------- one-time weight fragments: only 2 o-subtiles (32 VGPRs) ----------
    bf16x8 wcf[2][4];                 // [o-subtile][k-frag], B operand
    #pragma unroll
    for (int s = 0; s < 2; ++s)
      #pragma unroll
      for (int kf = 0; kf < 4; ++kf)
        #pragma unroll
        for (int j = 0; j < 8; ++j)
          wcf[s][kf][j] = f2bf(wc[((oh + s) * 16 + m) * CP + kf * 32 + g * 8 + j]);

    bf16x8 wmf[2];                    // wm: 32x31 padded to 32x32 (A operand)
    #pragma unroll
    for (int t2 = 0; t2 < 2; ++t2)
      #pragma unroll
      for (int j = 0; j < 8; ++j) {
        const int c = g * 8 + j;
        wmf[t2][j] = (c < CT) ? f2bf(wm[(t2 * 16 + m) * CT + c]) : (short)0;
      }
    float wff[8]; f32x4 bmf[2]; float bcf[2];
    #pragma unroll
    for (int t2 = 0; t2 < 2; ++t2)
      #pragma unroll
      for (int r = 0; r < 4; ++r) {
        wff[t2 * 4 + r] = wf[t2 * 16 + g * 4 + r];
        bmf[t2][r]      = bm[t2 * 16 + g * 4 + r];
      }
    #pragma unroll
    for (int s = 0; s < 2; ++s) bcf[s] = bc[(oh + s) * 16 + m];
    const float bfv = bf[0];

    const float* tbase = tin + (size_t)b * CT * HW;
    const float* pbase = poi + (size_t)b * CP * HW;
    float*       obase = out + (size_t)b * CO * HW;

    #pragma unroll
    for (int t = 0; t < 2; ++t) {
        const int pxt = px0 + t * 16;
        const float* tb = tbase + pxt + m;
        const float* pb = pbase + pxt + m;

        // ---- issue ALL 40 tile loads up front (tf first: consumed first) ----
        float tfr[8];
        #pragma unroll
        for (int j = 0; j < 8; ++j) {
            const int c = g * 8 + j;
            tfr[j] = (c < CT) ? tb[(size_t)c * HW] : 0.f;
        }
        float pfr[32];
        #pragma unroll
        for (int kf = 0; kf < 4; ++kf)
          #pragma unroll
          for (int j = 0; j < 8; ++j)
            pfr[kf * 8 + j] = pb[(size_t)(kf * 32 + g * 8 + j) * HW];
        __builtin_amdgcn_sched_barrier(0);   // keep loads hoisted above all VALU

        // ---- stage 1: tval = relu(wf . relu(wm@time + bm) + bf) ----
        bf16x8 tf;
        #pragma unroll
        for (int j = 0; j < 8; ++j) tf[j] = f2bf(tfr[j]);
        f32x4 z0 = __builtin_amdgcn_mfma_f32_16x16x32_bf16(wmf[0], tf, bmf[0], 0, 0, 0);
        f32x4 z1 = __builtin_amdgcn_mfma_f32_16x16x32_bf16(wmf[1], tf, bmf[1], 0, 0, 0);
        float s1 = 0.f;
        #pragma unroll
        for (int r = 0; r < 4; ++r) {
            s1 = fmaf(fmaxf(z0[r], 0.f), wff[r],     s1);
            s1 = fmaf(fmaxf(z1[r], 0.f), wff[4 + r], s1);
        }
        s1 += __shfl_xor(s1, 16, 64);         // sum hidden across lane-groups
        s1 += __shfl_xor(s1, 32, 64);
        const float tval = fmaxf(s1 + bfv, 0.f);   // valid for px = pxt + m
        f32x4 tv;                                  // transpose to D-row layout
        #pragma unroll
        for (int r = 0; r < 4; ++r) tv[r] = __shfl(tval, g * 4 + r, 64);

        // ---- stage 2: A = poi (M=px), B = wc (N=o), K=128 in 4 MFMAs ----
        bf16x8 pfv[4];
        #pragma unroll
        for (int kf = 0; kf < 4; ++kf)
          #pragma unroll
          for (int j = 0; j < 8; ++j)
            pfv[kf][j] = f2bf(pfr[kf * 8 + j]);

        float* ob = obase + pxt + g * 4;           // lane's 4-px store base
        #pragma unroll
        for (int s = 0; s < 2; ++s) {
            f32x4 a = {0.f, 0.f, 0.f, 0.f};
            #pragma unroll
            for (int kf = 0; kf < 4; ++kf)
                a = __builtin_amdgcn_mfma_f32_16x16x32_bf16(pfv[kf], wcf[s][kf], a, 0, 0, 0);
            f32x4 v;
            #pragma unroll
            for (int r = 0; r < 4; ++r) v[r] = fmaf(tv[r], a[r], bcf[s]);
            __builtin_nontemporal_store(
                v, reinterpret_cast<f32x4*>(ob + (size_t)((oh + s) * 16 + m) * HW));
        }
    }
}

extern "C" void kernel_launch(void* const* d_in, const int* in_sizes, int n_in,
                              void* d_out, int out_size, void* d_ws, size_t ws_size,
                              hipStream_t stream) {
    const float* poi = (const float*)d_in[0];
    const float* tin = (const float*)d_in[1];
    const float* wm  = (const float*)d_in[2];
    const float* bm  = (const float*)d_in[3];
    const float* wf  = (const float*)d_in[4];
    const float* bf  = (const float*)d_in[5];
    const float* wc  = (const float*)d_in[6];
    const float* bc  = (const float*)d_in[7];
    float* out = (float*)d_out;

    // 32 images x 64 strips; block = 2 px-halves x 2 o-halves = 4 waves
    hipLaunchKernelGGL(poi_mfma5, dim3(2048), dim3(256), 0, stream,
                       poi, tin, wm, bm, wf, bf, wc, bc, out);
}